// Round 3
// baseline (21.169 us; speedup 1.0000x reference)
//
#include <hip/hip_runtime.h>

// MipNeRF coarse cast + blur/inverse-CDF resample + fine cast.
// One 64-lane wave per ray. Coarse cast is LDS-free (bins closed-form in
// index; each lane computes the two frustums covering its float4 span).
// LDS only for cdf + t_fine. float4 stores for means/covs (16B-aligned).
// 256-thread blocks = 4 waves = 4 rays; grid = 8192/4.

constexpr int B_RAYS = 8192;
constexpr int S      = 128;
constexpr int SP1    = 129;
constexpr float F32_EPS = 1.1920928955078125e-07f;

// flat output offsets (t_coarse, means_c, covs_c, t_fine, means_f, covs_f)
constexpr long long O_TC = 0;
constexpr long long O_MC = O_TC + (long long)B_RAYS * SP1;
constexpr long long O_CC = O_MC + (long long)B_RAYS * S * 3;
constexpr long long O_TF = O_CC + (long long)B_RAYS * S * 3;
constexpr long long O_MF = O_TF + (long long)B_RAYS * SP1;
constexpr long long O_CF = O_MF + (long long)B_RAYS * S * 3;

struct Frust { float tm, tv, rv; };

__device__ __forceinline__ Frust frustum(float t0, float t1, float rad2)
{
    // conical_frustum_to_gaussian, stable branch
    Frust f;
    float mu  = 0.5f * (t0 + t1);
    float hw  = 0.5f * (t1 - t0);
    float mu2 = mu * mu, hw2 = hw * hw, hw4 = hw2 * hw2;
    float den = 3.0f * mu2 + hw2, rden = 1.0f / den;
    f.tm = mu + (2.0f * mu * hw2) * rden;
    f.tv = hw2 * (1.0f / 3.0f)
         - (4.0f / 15.0f) * (hw4 * (12.0f * mu2 - hw2)) * (rden * rden);
    f.rv = rad2 * (0.25f * mu2 + (5.0f / 12.0f) * hw2 - (4.0f / 15.0f) * hw4 * rden);
    return f;
}

__device__ __forceinline__ float sel3(int c, float x, float y, float z)
{
    return (c == 0) ? x : ((c == 1) ? y : z);
}

__global__ __launch_bounds__(256) void mipnerf_kernel(
    const float* __restrict__ origins,
    const float* __restrict__ directions,
    const float* __restrict__ radii,
    const float* __restrict__ nearp,
    const float* __restrict__ farp,
    const float* __restrict__ weights,
    float* __restrict__ out)
{
    const int tid = threadIdx.x;
    const int w   = tid >> 6;
    const int l   = tid & 63;
    const int b   = (blockIdx.x << 2) + w;

    __shared__ float s_cdf[4][132];
    __shared__ float s_tf[4][132];

    // issue all input loads up front (latency overlaps coarse compute)
    const float2 wv = *reinterpret_cast<const float2*>(weights + (long long)b * S + 2*l);
    const float ox = origins[3*b+0], oy = origins[3*b+1], oz = origins[3*b+2];
    const float dx = directions[3*b+0], dy = directions[3*b+1], dz = directions[3*b+2];
    const float rad = radii[b];
    const float nv = nearp[b], fv = farp[b];

    const float rad2  = rad * rad;
    const float dmag2 = fmaxf(dx*dx + dy*dy + dz*dz, 1e-10f);
    const float axx = dx*dx, ayy = dy*dy, azz = dz*dz;
    const float nxx = 1.0f - axx/dmag2, nyy = 1.0f - ayy/dmag2, nzz = 1.0f - azz/dmag2;

    auto bin = [&](int k) {
        float t = (float)k * (1.0f / 128.0f);
        return nv * (1.0f - t) + fv * t;
    };

    // emit float4 of means + float4 of covs for float indices [4m, 4m+4)
    // given t-values at intervals k0,k0+1 (ta=t[k0], tb=t[k0+1], tc=t[k0+2]).
    auto emit4 = [&](float ta, float tb, float tc, int m,
                     float* __restrict__ om, float* __restrict__ oc) {
        Frust A = frustum(ta, tb, rad2);
        Frust B = frustum(tb, tc, rad2);
        int r = m - 3 * (m / 3);          // 4m = 3*k0 + r
        float4 mv, cv;
        #pragma unroll
        for (int e = 0; e < 4; ++e) {
            int  rc   = r + e;
            bool useB = rc >= 3;
            int  c    = useB ? rc - 3 : rc;
            float tm = useB ? B.tm : A.tm;
            float tv = useB ? B.tv : A.tv;
            float rv = useB ? B.rv : A.rv;
            (&mv.x)[e] = sel3(c, dx, dy, dz) * tm + sel3(c, ox, oy, oz);
            (&cv.x)[e] = tv * sel3(c, axx, ayy, azz) + rv * sel3(c, nxx, nyy, nzz);
        }
        *reinterpret_cast<float4*>(om + 4*m) = mv;
        *reinterpret_cast<float4*>(oc + 4*m) = cv;
    };

    // ---- t_coarse (129 values, closed form) ----
    {
        float* ot = out + O_TC + (long long)b * SP1;
        ot[l]      = bin(l);
        ot[l + 64] = bin(l + 64);
        if (l == 0) ot[128] = bin(128);
    }

    // ---- coarse cast: LDS-free, float4 stores ----
    {
        float* om = out + O_MC + (long long)b * 384;
        float* oc = out + O_CC + (long long)b * 384;
        int m  = l;
        int k0 = m + m / 3;
        emit4(bin(k0), bin(k0 + 1), bin(k0 + 2), m, om, oc);
        if (l < 32) {
            m  = l + 64;
            k0 = m + m / 3;
            emit4(bin(k0), bin(k0 + 1), bin(k0 + 2), m, om, oc);
        }
    }

    // ---- blur weights (pair layout: lane holds w[2l], w[2l+1]) ----
    float wprev = __shfl_up(wv.y, 1);   if (l == 0)  wprev = wv.x;
    float wnext = __shfl_down(wv.x, 1); if (l == 63) wnext = wv.y;
    float m0 = fmaxf(wprev, wv.x), m1 = fmaxf(wv.x, wv.y), m2 = fmaxf(wv.y, wnext);
    float wb0 = 0.5f * (m0 + m1) + 0.01f;
    float wb1 = 0.5f * (m1 + m2) + 0.01f;

    // ---- inclusive scan of pair sums over 64 lanes ----
    float ps   = wb0 + wb1;
    float incl = ps;
    #pragma unroll
    for (int off = 1; off < 64; off <<= 1) {
        float y = __shfl_up(incl, off);
        if (l >= off) incl += y;
    }
    float total = __shfl(incl, 63);
    float pad   = fmaxf(1e-5f - total, 0.0f);
    float wstot = total + pad;
    float inv   = 1.0f / wstot;
    float padk  = pad * (1.0f / 128.0f);
    float excl  = incl - ps;

    // cdf[0]=0; cdf[k]=min(cumsum(pdf)[k-1],1), k=1..127; cdf[128]=1
    float c1 = fminf((excl + wb0 + (float)(2*l + 1) * padk) * inv, 1.0f);
    float c2 = fminf((incl        + (float)(2*l + 2) * padk) * inv, 1.0f);
    s_cdf[w][2*l + 1] = c1;
    s_cdf[w][2*l + 2] = (l == 63) ? 1.0f : c2;
    if (l == 0) s_cdf[w][0] = 0.0f;
    __builtin_amdgcn_wave_barrier();

    // ---- inverse-CDF: 3 binary searches interleaved (s = l, l+64, 128) ----
    const float ustep = (1.0f - F32_EPS) * (1.0f / 128.0f);
    const float u0 = (float)l * ustep;
    const float u1 = (float)(l + 64) * ustep;
    const float u2 = 128.0f * ustep;
    int lo0 = 0, hi0 = 128, lo1 = 0, hi1 = 128, lo2 = 0, hi2 = 128;
    #pragma unroll
    for (int it = 0; it < 7; ++it) {
        int q0 = (lo0 + hi0) >> 1, q1 = (lo1 + hi1) >> 1, q2 = (lo2 + hi2) >> 1;
        float a0 = s_cdf[w][q0], a1 = s_cdf[w][q1], a2 = s_cdf[w][q2];
        if (a0 <= u0) lo0 = q0; else hi0 = q0;
        if (a1 <= u1) lo1 = q1; else hi1 = q1;
        if (a2 <= u2) lo2 = q2; else hi2 = q2;
    }
    auto interp = [&](float u, int lo) {
        float c0  = s_cdf[w][lo], cg1 = s_cdf[w][lo + 1];
        float tt  = (u - c0) / (cg1 - c0);
        if (!(tt == tt)) tt = 0.0f;              // nan_to_num
        tt = fminf(fmaxf(tt, 0.0f), 1.0f);       // clip (inf -> 1)
        float b0 = bin(lo);
        return b0 + tt * (bin(lo + 1) - b0);
    };
    float tf0 = interp(u0, lo0);
    float tf1 = interp(u1, lo1);
    float tf2 = interp(u2, lo2);
    {
        float* ot = out + O_TF + (long long)b * SP1;
        s_tf[w][l]      = tf0;  ot[l]      = tf0;
        s_tf[w][l + 64] = tf1;  ot[l + 64] = tf1;
        if (l == 0) { s_tf[w][128] = tf2; ot[128] = tf2; }
    }
    __builtin_amdgcn_wave_barrier();

    // ---- fine cast: 3 LDS gathers per float4 span ----
    {
        float* om = out + O_MF + (long long)b * 384;
        float* oc = out + O_CF + (long long)b * 384;
        int m  = l;
        int k0 = m + m / 3;
        emit4(s_tf[w][k0], s_tf[w][k0 + 1], s_tf[w][k0 + 2], m, om, oc);
        if (l < 32) {
            m  = l + 64;
            k0 = m + m / 3;
            emit4(s_tf[w][k0], s_tf[w][k0 + 1], s_tf[w][k0 + 2], m, om, oc);
        }
    }
}

extern "C" void kernel_launch(void* const* d_in, const int* in_sizes, int n_in,
                              void* d_out, int out_size, void* d_ws, size_t ws_size,
                              hipStream_t stream)
{
    const float* origins    = (const float*)d_in[0];
    const float* directions = (const float*)d_in[1];
    const float* radii      = (const float*)d_in[2];
    const float* nearp      = (const float*)d_in[3];
    const float* farp       = (const float*)d_in[4];
    const float* weights    = (const float*)d_in[5];
    float* out = (float*)d_out;

    mipnerf_kernel<<<B_RAYS / 4, 256, 0, stream>>>(
        origins, directions, radii, nearp, farp, weights, out);
}

// Round 4
// 17.953 us; speedup vs baseline: 1.1791x; 1.1791x over previous
//
#include <hip/hip_runtime.h>

// MipNeRF coarse cast + blur/inverse-CDF resample + fine cast.
// One 64-lane wave per ray; 4 waves/block; grid 2048.
// VALU-minimized: frustum computed ONCE per interval (2/lane) into LDS,
// float4 output stores, all divisions replaced by v_rcp_f32.

constexpr int B_RAYS = 8192;
constexpr int S      = 128;
constexpr int SP1    = 129;
constexpr float F32_EPS = 1.1920928955078125e-07f;

// flat output offsets (t_coarse, means_c, covs_c, t_fine, means_f, covs_f)
constexpr long long O_TC = 0;
constexpr long long O_MC = O_TC + (long long)B_RAYS * SP1;
constexpr long long O_CC = O_MC + (long long)B_RAYS * S * 3;
constexpr long long O_TF = O_CC + (long long)B_RAYS * S * 3;
constexpr long long O_MF = O_TF + (long long)B_RAYS * SP1;
constexpr long long O_CF = O_MF + (long long)B_RAYS * S * 3;

__device__ __forceinline__ float frcp(float x) { return __builtin_amdgcn_rcpf(x); }

// conical_frustum_to_gaussian, stable branch (v_rcp instead of exact div;
// ~1ulp, threshold is 0.18)
__device__ __forceinline__ void frustum(float t0, float t1, float rad2,
                                        float& tm, float& tv, float& rv)
{
    float mu  = 0.5f * (t0 + t1);
    float hw  = 0.5f * (t1 - t0);
    float mu2 = mu * mu, hw2 = hw * hw, hw4 = hw2 * hw2;
    float den  = fmaf(3.0f, mu2, hw2);
    float rden = frcp(den);
    tm = fmaf(2.0f * mu * hw2, rden, mu);
    tv = hw2 * (1.0f / 3.0f)
       - (4.0f / 15.0f) * (hw4 * fmaf(12.0f, mu2, -hw2)) * (rden * rden);
    rv = rad2 * (0.25f * mu2 + (5.0f / 12.0f) * hw2 - (4.0f / 15.0f) * hw4 * rden);
}

__device__ __forceinline__ float sel3(int c, float x, float y, float z)
{
    return (c == 0) ? x : ((c == 1) ? y : z);
}

__global__ __launch_bounds__(256) void mipnerf_kernel(
    const float* __restrict__ origins,
    const float* __restrict__ directions,
    const float* __restrict__ radii,
    const float* __restrict__ nearp,
    const float* __restrict__ farp,
    const float* __restrict__ weights,
    float* __restrict__ out)
{
    const int tid = threadIdx.x;
    const int w   = tid >> 6;
    const int l   = tid & 63;
    const int b   = (blockIdx.x << 2) + w;

    __shared__ float2 s_ft[4][128];   // (t_mean, t_var) per interval
    __shared__ float  s_rv[4][128];   // r_var per interval
    __shared__ float  s_cdf[4][132];
    __shared__ float  s_tf[4][132];

    // issue all input loads up front
    const float2 wv = *reinterpret_cast<const float2*>(weights + (long long)b * S + 2*l);
    const float ox = origins[3*b+0], oy = origins[3*b+1], oz = origins[3*b+2];
    const float dx = directions[3*b+0], dy = directions[3*b+1], dz = directions[3*b+2];
    const float rad = radii[b];
    const float nv = nearp[b], fv = farp[b];

    const float rad2   = rad * rad;
    const float axx = dx*dx, ayy = dy*dy, azz = dz*dz;
    const float dmag2  = fmaxf(axx + ayy + azz, 1e-10f);
    const float rdmag2 = frcp(dmag2);
    const float nxx = 1.0f - axx * rdmag2;
    const float nyy = 1.0f - ayy * rdmag2;
    const float nzz = 1.0f - azz * rdmag2;

    auto bin = [&](int k) {
        float t = (float)k * (1.0f / 128.0f);
        return nv * (1.0f - t) + fv * t;
    };

    // ---- t_coarse (closed form) ----
    {
        float* ot = out + O_TC + (long long)b * SP1;
        ot[l]      = bin(l);
        ot[l + 64] = bin(l + 64);
        if (l == 0) ot[128] = bin(128);
    }

    // ---- coarse frustum once per interval -> LDS ----
    #pragma unroll
    for (int j = 0; j < 2; ++j) {
        int i = l + 64*j;
        float tm, tv, rv;
        frustum(bin(i), bin(i + 1), rad2, tm, tv, rv);
        s_ft[w][i] = make_float2(tm, tv);
        s_rv[w][i] = rv;
    }
    __builtin_amdgcn_wave_barrier();

    // emit float4 means + float4 covs for span m (floats [4m,4m+4), intervals k0,k0+1)
    auto emit_span = [&](int m, float* __restrict__ om, float* __restrict__ oc) {
        int k0 = m + m / 3;            // floor(4m/3)
        int r  = 4*m - 3*k0;
        float2 fA = s_ft[w][k0], fB = s_ft[w][k0 + 1];
        float  rA = s_rv[w][k0], rB = s_rv[w][k0 + 1];
        float4 mv, cv;
        #pragma unroll
        for (int e = 0; e < 4; ++e) {
            int  rc   = r + e;
            bool useB = rc >= 3;
            int  c    = useB ? rc - 3 : rc;
            float tm = useB ? fB.x : fA.x;
            float tv = useB ? fB.y : fA.y;
            float rv = useB ? rB   : rA;
            (&mv.x)[e] = sel3(c, dx, dy, dz) * tm + sel3(c, ox, oy, oz);
            (&cv.x)[e] = tv * sel3(c, axx, ayy, azz) + rv * sel3(c, nxx, nyy, nzz);
        }
        *reinterpret_cast<float4*>(om + 4*m) = mv;
        *reinterpret_cast<float4*>(oc + 4*m) = cv;
    };

    // ---- coarse emit (96 spans per region) ----
    {
        float* om = out + O_MC + (long long)b * 384;
        float* oc = out + O_CC + (long long)b * 384;
        emit_span(l, om, oc);
        if (l < 32) emit_span(l + 64, om, oc);
    }

    // ---- blur weights (pair layout: lane holds w[2l], w[2l+1]) ----
    float wprev = __shfl_up(wv.y, 1);   if (l == 0)  wprev = wv.x;
    float wnext = __shfl_down(wv.x, 1); if (l == 63) wnext = wv.y;
    float m0 = fmaxf(wprev, wv.x), m1 = fmaxf(wv.x, wv.y), m2 = fmaxf(wv.y, wnext);
    float wb0 = 0.5f * (m0 + m1) + 0.01f;
    float wb1 = 0.5f * (m1 + m2) + 0.01f;

    // ---- inclusive scan of pair sums over 64 lanes ----
    float ps   = wb0 + wb1;
    float incl = ps;
    #pragma unroll
    for (int off = 1; off < 64; off <<= 1) {
        float y = __shfl_up(incl, off);
        if (l >= off) incl += y;
    }
    float total = __shfl(incl, 63);
    float pad   = fmaxf(1e-5f - total, 0.0f);
    float wstot = total + pad;
    float inv   = frcp(wstot);
    float padk  = pad * (1.0f / 128.0f);
    float excl  = incl - ps;

    // cdf[0]=0; cdf[k]=min(cumsum(pdf)[k-1],1), k=1..127; cdf[128]=1
    float c1 = fminf((excl + wb0 + (float)(2*l + 1) * padk) * inv, 1.0f);
    float c2 = fminf((incl        + (float)(2*l + 2) * padk) * inv, 1.0f);
    s_cdf[w][2*l + 1] = c1;
    s_cdf[w][2*l + 2] = (l == 63) ? 1.0f : c2;
    if (l == 0) s_cdf[w][0] = 0.0f;
    __builtin_amdgcn_wave_barrier();

    // ---- inverse-CDF: 3 binary searches interleaved (s = l, l+64, 128) ----
    const float ustep = (1.0f - F32_EPS) * (1.0f / 128.0f);
    const float u0 = (float)l * ustep;
    const float u1 = (float)(l + 64) * ustep;
    const float u2 = 128.0f * ustep;
    int lo0 = 0, hi0 = 128, lo1 = 0, hi1 = 128, lo2 = 0, hi2 = 128;
    #pragma unroll
    for (int it = 0; it < 7; ++it) {
        int q0 = (lo0 + hi0) >> 1, q1 = (lo1 + hi1) >> 1, q2 = (lo2 + hi2) >> 1;
        float a0 = s_cdf[w][q0], a1 = s_cdf[w][q1], a2 = s_cdf[w][q2];
        if (a0 <= u0) lo0 = q0; else hi0 = q0;
        if (a1 <= u1) lo1 = q1; else hi1 = q1;
        if (a2 <= u2) lo2 = q2; else hi2 = q2;
    }
    auto interp = [&](float u, int lo) {
        float c0  = s_cdf[w][lo], cg1 = s_cdf[w][lo + 1];
        float tt  = (u - c0) * frcp(cg1 - c0);
        if (!(tt == tt)) tt = 0.0f;              // nan_to_num (0/0 -> 0)
        tt = fminf(fmaxf(tt, 0.0f), 1.0f);       // clip (inf -> 1)
        float b0 = bin(lo);
        return fmaf(tt, bin(lo + 1) - b0, b0);
    };
    float tf0 = interp(u0, lo0);
    float tf1 = interp(u1, lo1);
    float tf2 = interp(u2, lo2);
    {
        float* ot = out + O_TF + (long long)b * SP1;
        s_tf[w][l]      = tf0;  ot[l]      = tf0;
        s_tf[w][l + 64] = tf1;  ot[l + 64] = tf1;
        if (l == 0) { s_tf[w][128] = tf2; ot[128] = tf2; }
    }
    __builtin_amdgcn_wave_barrier();

    // ---- fine frustum once per interval -> LDS (overwrite) ----
    #pragma unroll
    for (int j = 0; j < 2; ++j) {
        int i = l + 64*j;
        float tm, tv, rv;
        frustum(s_tf[w][i], s_tf[w][i + 1], rad2, tm, tv, rv);
        s_ft[w][i] = make_float2(tm, tv);
        s_rv[w][i] = rv;
    }
    __builtin_amdgcn_wave_barrier();

    // ---- fine emit ----
    {
        float* om = out + O_MF + (long long)b * 384;
        float* oc = out + O_CF + (long long)b * 384;
        emit_span(l, om, oc);
        if (l < 32) emit_span(l + 64, om, oc);
    }
}

extern "C" void kernel_launch(void* const* d_in, const int* in_sizes, int n_in,
                              void* d_out, int out_size, void* d_ws, size_t ws_size,
                              hipStream_t stream)
{
    const float* origins    = (const float*)d_in[0];
    const float* directions = (const float*)d_in[1];
    const float* radii      = (const float*)d_in[2];
    const float* nearp      = (const float*)d_in[3];
    const float* farp       = (const float*)d_in[4];
    const float* weights    = (const float*)d_in[5];
    float* out = (float*)d_out;

    mipnerf_kernel<<<B_RAYS / 4, 256, 0, stream>>>(
        origins, directions, radii, nearp, farp, weights, out);
}

// Round 5
// 17.794 us; speedup vs baseline: 1.1897x; 1.0090x over previous
//
#include <hip/hip_runtime.h>

// MipNeRF coarse cast + blur/inverse-CDF resample + fine cast.
// One 64-lane wave per ray, 64-thread blocks (uniform ray params -> s_load).
// Latency-chain minimized: DPP scan (no bpermute), run-scatter instead of
// binary search (1 LDS read per sample), DPP neighbor exchange for t_fine,
// float4 payloads/frustums, v_rcp for all divides, float4 output stores.

constexpr int B_RAYS = 8192;
constexpr int S      = 128;
constexpr int SP1    = 129;
constexpr float F32_EPS = 1.1920928955078125e-07f;
constexpr float USTEP   = (1.0f - F32_EPS) / 128.0f;     // exact: (1-2^-23)/2^7
constexpr float R_SCALE = 128.0f / (1.0f - F32_EPS);

// flat output offsets (t_coarse, means_c, covs_c, t_fine, means_f, covs_f)
constexpr long long O_TC = 0;
constexpr long long O_MC = O_TC + (long long)B_RAYS * SP1;
constexpr long long O_CC = O_MC + (long long)B_RAYS * S * 3;
constexpr long long O_TF = O_CC + (long long)B_RAYS * S * 3;
constexpr long long O_MF = O_TF + (long long)B_RAYS * SP1;
constexpr long long O_CF = O_MF + (long long)B_RAYS * S * 3;

__device__ __forceinline__ float frcp(float x) { return __builtin_amdgcn_rcpf(x); }

template<int CTRL, int RM>
__device__ __forceinline__ float dpp_addf(float x) {
    int m = __builtin_amdgcn_update_dpp(0, __builtin_bit_cast(int, x),
                                        CTRL, RM, 0xF, true);
    return x + __builtin_bit_cast(float, m);
}
template<int CTRL>
__device__ __forceinline__ float dpp_movf(float x) {
    int m = __builtin_amdgcn_update_dpp(0, __builtin_bit_cast(int, x),
                                        CTRL, 0xF, 0xF, true);
    return __builtin_bit_cast(float, m);
}

// conical_frustum_to_gaussian, stable branch (rcp instead of exact div)
__device__ __forceinline__ void frustum(float t0, float t1, float rad2,
                                        float& tm, float& tv, float& rv)
{
    float mu  = 0.5f * (t0 + t1);
    float hw  = 0.5f * (t1 - t0);
    float mu2 = mu * mu, hw2 = hw * hw, hw4 = hw2 * hw2;
    float den  = fmaf(3.0f, mu2, hw2);
    float rden = frcp(den);
    tm = fmaf(2.0f * mu * hw2, rden, mu);
    tv = hw2 * (1.0f / 3.0f)
       - (4.0f / 15.0f) * (hw4 * fmaf(12.0f, mu2, -hw2)) * (rden * rden);
    rv = rad2 * (0.25f * mu2 + (5.0f / 12.0f) * hw2 - (4.0f / 15.0f) * hw4 * rden);
}

__device__ __forceinline__ float sel3(int c, float x, float y, float z)
{
    return (c == 0) ? x : ((c == 1) ? y : z);
}

// smallest s in [0,129] with (float)s * USTEP >= c  (exact predicate)
__device__ __forceinline__ int smin_of(float c)
{
    int s = (int)ceilf(c * R_SCALE);
    s = s < 0 ? 0 : (s > 129 ? 129 : s);
    #pragma unroll
    for (int it = 0; it < 2; ++it)
        if (s > 0 && (float)(s - 1) * USTEP >= c) --s;
    #pragma unroll
    for (int it = 0; it < 2; ++it)
        if (s < 129 && (float)s * USTEP < c) ++s;
    return s;
}

__global__ __launch_bounds__(64) void mipnerf_kernel(
    const float* __restrict__ origins,
    const float* __restrict__ directions,
    const float* __restrict__ radii,
    const float* __restrict__ nearp,
    const float* __restrict__ farp,
    const float* __restrict__ weights,
    float* __restrict__ out)
{
    const int l = threadIdx.x;      // lane
    const int b = blockIdx.x;       // ray (wave-uniform -> scalar loads)

    __shared__ float4 s_pay[132];   // per-sample {c0, dc, b0, b1}
    __shared__ float4 s_fr[128];    // per-interval {t_mean, t_var, r_var, -}

    // per-lane weights; per-ray params are uniform (compiler -> s_load)
    const float2 wv = *reinterpret_cast<const float2*>(weights + (long long)b * S + 2*l);
    const float ox = origins[3*b+0], oy = origins[3*b+1], oz = origins[3*b+2];
    const float dx = directions[3*b+0], dy = directions[3*b+1], dz = directions[3*b+2];
    const float rad = radii[b];
    const float nv = nearp[b], fv = farp[b];

    const float rad2   = rad * rad;
    const float axx = dx*dx, ayy = dy*dy, azz = dz*dz;
    const float dmag2  = fmaxf(axx + ayy + azz, 1e-10f);
    const float rdmag2 = frcp(dmag2);
    const float nxx = 1.0f - axx * rdmag2;
    const float nyy = 1.0f - ayy * rdmag2;
    const float nzz = 1.0f - azz * rdmag2;

    auto bin = [&](int k) {
        float t = (float)k * (1.0f / 128.0f);
        return nv * (1.0f - t) + fv * t;     // bit-identical to reference
    };

    // ---- t_coarse out ----
    {
        float* ot = out + O_TC + (long long)b * SP1;
        ot[l]      = bin(l);
        ot[l + 64] = bin(l + 64);
        if (l == 0) ot[128] = bin(128);
    }

    // ---- coarse frustum (2 intervals/lane) -> LDS float4 ----
    #pragma unroll
    for (int j = 0; j < 2; ++j) {
        int i = l + 64*j;
        float tm, tv, rv;
        frustum(bin(i), bin(i + 1), rad2, tm, tv, rv);
        s_fr[i] = make_float4(tm, tv, rv, 0.0f);
    }
    __builtin_amdgcn_wave_barrier();

    // emit float4 means + float4 covs for span m (floats [4m,4m+4))
    auto emit_span = [&](int m, float* __restrict__ om, float* __restrict__ oc) {
        int k0 = m + m / 3;            // floor(4m/3)
        int r  = 4*m - 3*k0;
        float4 fA = s_fr[k0], fB = s_fr[k0 + 1];
        float4 mv, cv;
        #pragma unroll
        for (int e = 0; e < 4; ++e) {
            int  rc   = r + e;
            bool useB = rc >= 3;
            int  c    = useB ? rc - 3 : rc;
            float tm = useB ? fB.x : fA.x;
            float tv = useB ? fB.y : fA.y;
            float rv = useB ? fB.z : fA.z;
            (&mv.x)[e] = sel3(c, dx, dy, dz) * tm + sel3(c, ox, oy, oz);
            (&cv.x)[e] = tv * sel3(c, axx, ayy, azz) + rv * sel3(c, nxx, nyy, nzz);
        }
        *reinterpret_cast<float4*>(om + 4*m) = mv;
        *reinterpret_cast<float4*>(oc + 4*m) = cv;
    };

    // ---- coarse emit ----
    {
        float* om = out + O_MC + (long long)b * 384;
        float* oc = out + O_CC + (long long)b * 384;
        emit_span(l, om, oc);
        if (l < 32) emit_span(l + 64, om, oc);
    }

    // ---- blur weights (lane holds w[2l], w[2l+1]); DPP +-1 shifts ----
    float wprev = dpp_movf<0x138>(wv.y);  if (l == 0)  wprev = wv.x;  // wave_shr:1
    float wnext = dpp_movf<0x130>(wv.x);  if (l == 63) wnext = wv.y;  // wave_shl:1
    float m0 = fmaxf(wprev, wv.x), m1 = fmaxf(wv.x, wv.y), m2 = fmaxf(wv.y, wnext);
    float wb0 = 0.5f * (m0 + m1) + 0.01f;
    float wb1 = 0.5f * (m1 + m2) + 0.01f;

    // ---- wave64 inclusive scan of pair sums via DPP (6 VALU adds) ----
    float ps = wb0 + wb1;
    float x  = ps;
    x = dpp_addf<0x111, 0xF>(x);   // row_shr:1
    x = dpp_addf<0x112, 0xF>(x);   // row_shr:2
    x = dpp_addf<0x114, 0xF>(x);   // row_shr:4
    x = dpp_addf<0x118, 0xF>(x);   // row_shr:8
    x = dpp_addf<0x142, 0xA>(x);   // row_bcast15 -> rows 1,3
    x = dpp_addf<0x143, 0xC>(x);   // row_bcast31 -> rows 2,3
    float incl  = x;
    float total = __builtin_bit_cast(float,
        __builtin_amdgcn_readlane(__builtin_bit_cast(int, incl), 63));

    float pad   = fmaxf(1e-5f - total, 0.0f);
    float wstot = total + pad;
    float inv   = frcp(wstot);
    float padk  = pad * (1.0f / 128.0f);
    float excl  = incl - ps;

    // cdf entries this lane owns: B=cdf[2l+1], C=cdf[2l+2]; A=cdf[2l] via DPP
    float Bv = fminf((excl + wb0 + (float)(2*l + 1) * padk) * inv, 1.0f);
    float Cv = (l == 63) ? 1.0f
             : fminf((incl + (float)(2*l + 2) * padk) * inv, 1.0f);
    float Av = dpp_movf<0x138>(Cv);          // wave_shr:1; lane0 -> 0.0 = cdf[0]

    // ---- run-scatter: interval k owns samples [smin(cdf[k]), smin(cdf[k+1])) ----
    int sm0 = smin_of(Av);
    int sm1 = smin_of(Bv);
    int sm2 = smin_of(Cv);                   // l==63: smin(1.0)=129 sentinel
    {
        float4 payA = make_float4(Av, Bv - Av, bin(2*l),     bin(2*l + 1));
        float4 payB = make_float4(Bv, Cv - Bv, bin(2*l + 1), bin(2*l + 2));
        for (int s2 = sm0; s2 < sm1; ++s2) s_pay[s2] = payA;
        for (int s2 = sm1; s2 < sm2; ++s2) s_pay[s2] = payB;
    }
    __builtin_amdgcn_wave_barrier();

    // ---- sample: ONE b128 read per sample ----
    auto sample_one = [&](int s) -> float {
        float4 p = s_pay[s];
        float u  = (float)s * USTEP;
        float tt = (u - p.x) * frcp(p.y);
        if (!(tt == tt)) tt = 0.0f;              // nan_to_num
        tt = fminf(fmaxf(tt, 0.0f), 1.0f);       // clip (inf -> 1)
        return p.z + tt * (p.w - p.z);
    };
    float tf0 = sample_one(l);
    float tf1 = sample_one(l + 64);
    float tf2 = sample_one(128);                 // uniform addr -> broadcast read
    {
        float* ot = out + O_TF + (long long)b * SP1;
        ot[l]      = tf0;
        ot[l + 64] = tf1;
        if (l == 0) ot[128] = tf2;
    }

    // ---- fine frustum: neighbors via DPP, no LDS round-trip for t ----
    float tf1_0 = __builtin_bit_cast(float,
        __builtin_amdgcn_readfirstlane(__builtin_bit_cast(int, tf1))); // t_fine[64]
    float tA1 = dpp_movf<0x130>(tf0);  if (l == 63) tA1 = tf1_0;   // t_fine[l+1]
    float tB1 = dpp_movf<0x130>(tf1);  if (l == 63) tB1 = tf2;     // t_fine[l+65]
    {
        float tm, tv, rv;
        frustum(tf0, tA1, rad2, tm, tv, rv);
        s_fr[l] = make_float4(tm, tv, rv, 0.0f);
        frustum(tf1, tB1, rad2, tm, tv, rv);
        s_fr[l + 64] = make_float4(tm, tv, rv, 0.0f);
    }
    __builtin_amdgcn_wave_barrier();

    // ---- fine emit ----
    {
        float* om = out + O_MF + (long long)b * 384;
        float* oc = out + O_CF + (long long)b * 384;
        emit_span(l, om, oc);
        if (l < 32) emit_span(l + 64, om, oc);
    }
}

extern "C" void kernel_launch(void* const* d_in, const int* in_sizes, int n_in,
                              void* d_out, int out_size, void* d_ws, size_t ws_size,
                              hipStream_t stream)
{
    const float* origins    = (const float*)d_in[0];
    const float* directions = (const float*)d_in[1];
    const float* radii      = (const float*)d_in[2];
    const float* nearp      = (const float*)d_in[3];
    const float* farp       = (const float*)d_in[4];
    const float* weights    = (const float*)d_in[5];
    float* out = (float*)d_out;

    mipnerf_kernel<<<B_RAYS, 64, 0, stream>>>(
        origins, directions, radii, nearp, farp, weights, out);
}

// Round 7
// 17.345 us; speedup vs baseline: 1.2205x; 1.0259x over previous
//
#include <hip/hip_runtime.h>

// MipNeRF coarse cast + blur/inverse-CDF resample + fine cast.
// One 64-lane wave per ray; 256-thread blocks = 4 independent waves.
// R5 structure (DPP scan, run-scatter sampling, rcp divides, float4 stores)
// + NONTEMPORAL stores (clang ext_vector for the builtin) streaming past L2.

constexpr int B_RAYS = 8192;
constexpr int S      = 128;
constexpr int SP1    = 129;
constexpr float F32_EPS = 1.1920928955078125e-07f;
constexpr float USTEP   = (1.0f - F32_EPS) / 128.0f;
constexpr float R_SCALE = 128.0f / (1.0f - F32_EPS);

// flat output offsets (t_coarse, means_c, covs_c, t_fine, means_f, covs_f)
constexpr long long O_TC = 0;
constexpr long long O_MC = O_TC + (long long)B_RAYS * SP1;
constexpr long long O_CC = O_MC + (long long)B_RAYS * S * 3;
constexpr long long O_TF = O_CC + (long long)B_RAYS * S * 3;
constexpr long long O_MF = O_TF + (long long)B_RAYS * SP1;
constexpr long long O_CF = O_MF + (long long)B_RAYS * S * 3;

typedef float vf4 __attribute__((ext_vector_type(4)));

__device__ __forceinline__ float frcp(float x) { return __builtin_amdgcn_rcpf(x); }

template<int CTRL, int RM>
__device__ __forceinline__ float dpp_addf(float x) {
    int m = __builtin_amdgcn_update_dpp(0, __builtin_bit_cast(int, x),
                                        CTRL, RM, 0xF, true);
    return x + __builtin_bit_cast(float, m);
}
template<int CTRL>
__device__ __forceinline__ float dpp_movf(float x) {
    int m = __builtin_amdgcn_update_dpp(0, __builtin_bit_cast(int, x),
                                        CTRL, 0xF, 0xF, true);
    return __builtin_bit_cast(float, m);
}

__device__ __forceinline__ void st_nt(float* p, float v) {
    __builtin_nontemporal_store(v, p);
}
__device__ __forceinline__ void st_nt4(float* p, float4 v) {
    __builtin_nontemporal_store(__builtin_bit_cast(vf4, v),
                                reinterpret_cast<vf4*>(p));
}

// conical_frustum_to_gaussian, stable branch (rcp instead of exact div)
__device__ __forceinline__ void frustum(float t0, float t1, float rad2,
                                        float& tm, float& tv, float& rv)
{
    float mu  = 0.5f * (t0 + t1);
    float hw  = 0.5f * (t1 - t0);
    float mu2 = mu * mu, hw2 = hw * hw, hw4 = hw2 * hw2;
    float den  = fmaf(3.0f, mu2, hw2);
    float rden = frcp(den);
    tm = fmaf(2.0f * mu * hw2, rden, mu);
    tv = hw2 * (1.0f / 3.0f)
       - (4.0f / 15.0f) * (hw4 * fmaf(12.0f, mu2, -hw2)) * (rden * rden);
    rv = rad2 * (0.25f * mu2 + (5.0f / 12.0f) * hw2 - (4.0f / 15.0f) * hw4 * rden);
}

__device__ __forceinline__ float sel3(int c, float x, float y, float z)
{
    return (c == 0) ? x : ((c == 1) ? y : z);
}

// smallest s in [0,129] with (float)s * USTEP >= c  (exact predicate)
__device__ __forceinline__ int smin_of(float c)
{
    int s = (int)ceilf(c * R_SCALE);
    s = s < 0 ? 0 : (s > 129 ? 129 : s);
    #pragma unroll
    for (int it = 0; it < 2; ++it)
        if (s > 0 && (float)(s - 1) * USTEP >= c) --s;
    #pragma unroll
    for (int it = 0; it < 2; ++it)
        if (s < 129 && (float)s * USTEP < c) ++s;
    return s;
}

__global__ __launch_bounds__(256) void mipnerf_kernel(
    const float* __restrict__ origins,
    const float* __restrict__ directions,
    const float* __restrict__ radii,
    const float* __restrict__ nearp,
    const float* __restrict__ farp,
    const float* __restrict__ weights,
    float* __restrict__ out)
{
    const int tid = threadIdx.x;
    const int w   = tid >> 6;
    const int l   = tid & 63;
    const int b   = (blockIdx.x << 2) + w;

    __shared__ float4 s_pay[4][132];   // per-sample {c0, dc, b0, b1}
    __shared__ float4 s_fr[4][128];    // per-interval {t_mean, t_var, r_var, -}

    const float2 wv = *reinterpret_cast<const float2*>(weights + (long long)b * S + 2*l);
    const float ox = origins[3*b+0], oy = origins[3*b+1], oz = origins[3*b+2];
    const float dx = directions[3*b+0], dy = directions[3*b+1], dz = directions[3*b+2];
    const float rad = radii[b];
    const float nv = nearp[b], fv = farp[b];

    const float rad2   = rad * rad;
    const float axx = dx*dx, ayy = dy*dy, azz = dz*dz;
    const float dmag2  = fmaxf(axx + ayy + azz, 1e-10f);
    const float rdmag2 = frcp(dmag2);
    const float nxx = 1.0f - axx * rdmag2;
    const float nyy = 1.0f - ayy * rdmag2;
    const float nzz = 1.0f - azz * rdmag2;

    auto bin = [&](int k) {
        float t = (float)k * (1.0f / 128.0f);
        return nv * (1.0f - t) + fv * t;     // bit-identical to reference
    };

    // ---- t_coarse out ----
    {
        float* ot = out + O_TC + (long long)b * SP1;
        st_nt(ot + l,      bin(l));
        st_nt(ot + l + 64, bin(l + 64));
        if (l == 0) st_nt(ot + 128, bin(128));
    }

    // ---- coarse frustum (2 intervals/lane) -> LDS float4 ----
    #pragma unroll
    for (int j = 0; j < 2; ++j) {
        int i = l + 64*j;
        float tm, tv, rv;
        frustum(bin(i), bin(i + 1), rad2, tm, tv, rv);
        s_fr[w][i] = make_float4(tm, tv, rv, 0.0f);
    }
    __builtin_amdgcn_wave_barrier();

    // emit float4 means + float4 covs for span m (floats [4m,4m+4))
    auto emit_span = [&](int m, float* __restrict__ om, float* __restrict__ oc) {
        int k0 = m + m / 3;            // floor(4m/3)
        int r  = 4*m - 3*k0;
        float4 fA = s_fr[w][k0], fB = s_fr[w][k0 + 1];
        float4 mv, cv;
        #pragma unroll
        for (int e = 0; e < 4; ++e) {
            int  rc   = r + e;
            bool useB = rc >= 3;
            int  c    = useB ? rc - 3 : rc;
            float tm = useB ? fB.x : fA.x;
            float tv = useB ? fB.y : fA.y;
            float rv = useB ? fB.z : fA.z;
            (&mv.x)[e] = sel3(c, dx, dy, dz) * tm + sel3(c, ox, oy, oz);
            (&cv.x)[e] = tv * sel3(c, axx, ayy, azz) + rv * sel3(c, nxx, nyy, nzz);
        }
        st_nt4(om + 4*m, mv);
        st_nt4(oc + 4*m, cv);
    };

    // ---- coarse emit ----
    {
        float* om = out + O_MC + (long long)b * 384;
        float* oc = out + O_CC + (long long)b * 384;
        emit_span(l, om, oc);
        if (l < 32) emit_span(l + 64, om, oc);
    }

    // ---- blur weights (lane holds w[2l], w[2l+1]); DPP +-1 shifts ----
    float wprev = dpp_movf<0x138>(wv.y);  if (l == 0)  wprev = wv.x;  // wave_shr:1
    float wnext = dpp_movf<0x130>(wv.x);  if (l == 63) wnext = wv.y;  // wave_shl:1
    float m0 = fmaxf(wprev, wv.x), m1 = fmaxf(wv.x, wv.y), m2 = fmaxf(wv.y, wnext);
    float wb0 = 0.5f * (m0 + m1) + 0.01f;
    float wb1 = 0.5f * (m1 + m2) + 0.01f;

    // ---- wave64 inclusive scan of pair sums via DPP ----
    float ps = wb0 + wb1;
    float x  = ps;
    x = dpp_addf<0x111, 0xF>(x);   // row_shr:1
    x = dpp_addf<0x112, 0xF>(x);   // row_shr:2
    x = dpp_addf<0x114, 0xF>(x);   // row_shr:4
    x = dpp_addf<0x118, 0xF>(x);   // row_shr:8
    x = dpp_addf<0x142, 0xA>(x);   // row_bcast15 -> rows 1,3
    x = dpp_addf<0x143, 0xC>(x);   // row_bcast31 -> rows 2,3
    float incl  = x;
    float total = __builtin_bit_cast(float,
        __builtin_amdgcn_readlane(__builtin_bit_cast(int, incl), 63));

    float pad   = fmaxf(1e-5f - total, 0.0f);
    float wstot = total + pad;
    float inv   = frcp(wstot);
    float padk  = pad * (1.0f / 128.0f);
    float excl  = incl - ps;

    // cdf entries this lane owns: B=cdf[2l+1], C=cdf[2l+2]; A=cdf[2l] via DPP
    float Bv = fminf((excl + wb0 + (float)(2*l + 1) * padk) * inv, 1.0f);
    float Cv = (l == 63) ? 1.0f
             : fminf((incl + (float)(2*l + 2) * padk) * inv, 1.0f);
    float Av = dpp_movf<0x138>(Cv);          // wave_shr:1; lane0 -> 0.0 = cdf[0]

    // ---- run-scatter: interval k owns samples [smin(cdf[k]), smin(cdf[k+1])) ----
    int sm0 = smin_of(Av);
    int sm1 = smin_of(Bv);
    int sm2 = smin_of(Cv);                   // l==63: smin(1.0)=129 sentinel
    {
        float4 payA = make_float4(Av, Bv - Av, bin(2*l),     bin(2*l + 1));
        float4 payB = make_float4(Bv, Cv - Bv, bin(2*l + 1), bin(2*l + 2));
        for (int s2 = sm0; s2 < sm1; ++s2) s_pay[w][s2] = payA;
        for (int s2 = sm1; s2 < sm2; ++s2) s_pay[w][s2] = payB;
    }
    __builtin_amdgcn_wave_barrier();

    // ---- sample: ONE b128 read per sample ----
    auto sample_one = [&](int s) -> float {
        float4 p = s_pay[w][s];
        float u  = (float)s * USTEP;
        float tt = (u - p.x) * frcp(p.y);
        if (!(tt == tt)) tt = 0.0f;              // nan_to_num
        tt = fminf(fmaxf(tt, 0.0f), 1.0f);       // clip (inf -> 1)
        return p.z + tt * (p.w - p.z);
    };
    float tf0 = sample_one(l);
    float tf1 = sample_one(l + 64);
    float tf2 = sample_one(128);
    {
        float* ot = out + O_TF + (long long)b * SP1;
        st_nt(ot + l,      tf0);
        st_nt(ot + l + 64, tf1);
        if (l == 0) st_nt(ot + 128, tf2);
    }

    // ---- fine frustum: neighbors via DPP ----
    float tf1_0 = __builtin_bit_cast(float,
        __builtin_amdgcn_readfirstlane(__builtin_bit_cast(int, tf1))); // t_fine[64]
    float tA1 = dpp_movf<0x130>(tf0);  if (l == 63) tA1 = tf1_0;   // t_fine[l+1]
    float tB1 = dpp_movf<0x130>(tf1);  if (l == 63) tB1 = tf2;     // t_fine[l+65]
    {
        float tm, tv, rv;
        frustum(tf0, tA1, rad2, tm, tv, rv);
        s_fr[w][l] = make_float4(tm, tv, rv, 0.0f);
        frustum(tf1, tB1, rad2, tm, tv, rv);
        s_fr[w][l + 64] = make_float4(tm, tv, rv, 0.0f);
    }
    __builtin_amdgcn_wave_barrier();

    // ---- fine emit ----
    {
        float* om = out + O_MF + (long long)b * 384;
        float* oc = out + O_CF + (long long)b * 384;
        emit_span(l, om, oc);
        if (l < 32) emit_span(l + 64, om, oc);
    }
}

extern "C" void kernel_launch(void* const* d_in, const int* in_sizes, int n_in,
                              void* d_out, int out_size, void* d_ws, size_t ws_size,
                              hipStream_t stream)
{
    const float* origins    = (const float*)d_in[0];
    const float* directions = (const float*)d_in[1];
    const float* radii      = (const float*)d_in[2];
    const float* nearp      = (const float*)d_in[3];
    const float* farp       = (const float*)d_in[4];
    const float* weights    = (const float*)d_in[5];
    float* out = (float*)d_out;

    mipnerf_kernel<<<B_RAYS / 4, 256, 0, stream>>>(
        origins, directions, radii, nearp, farp, weights, out);
}